// Round 5
// baseline (417.805 us; speedup 1.0000x reference)
//
#include <hip/hip_runtime.h>
#include <hip/hip_bf16.h>

typedef __bf16 bf16_t;
typedef __attribute__((ext_vector_type(8))) __bf16 bf16x8;
typedef __attribute__((ext_vector_type(4))) __bf16 bf16x4;
typedef __attribute__((ext_vector_type(4))) float floatx4;
typedef __attribute__((ext_vector_type(4))) int intx4;
typedef __attribute__((ext_vector_type(4))) unsigned int uintx4;

#define NN 8192
#define FIN 256
#define FOUT 64
#define GAT_ALPHA 0.2f
#define JSPLIT 8
#define JSEG (NN / JSPLIT)          // 1024 j per wave
#define NSTEP (JSEG / 32)           // 32 MFMA steps of K=32

// ---------------------------------------------------------------------------
// Kernel A: h = input @ W (fp32 in -> bf16 MFMA). Outputs:
//   hT [64][8192] bf16, E1/F1 fp32 [8192], ef2 packed (bf16 E2 | bf16 F2<<16).
// ---------------------------------------------------------------------------
__global__ __launch_bounds__(256) void gat_h_kernel(
    const float* __restrict__ input,    // [8192][256] fp32
    const float* __restrict__ W,        // [256][64] fp32
    const float* __restrict__ a,        // [128] fp32
    bf16_t* __restrict__ hT,            // [64][8192] bf16
    float* __restrict__ e1g, float* __restrict__ f1g,
    unsigned* __restrict__ ef2g)        // [8192] packed bf16 pair
{
    alignas(16) __shared__ bf16_t in_lds[32][264];
    alignas(16) __shared__ bf16_t wt_lds[64][264];
    __shared__ float h_lds[32][65];

    const int t  = threadIdx.x;
    const int i0 = blockIdx.x * 32;

    #pragma unroll
    for (int v = 0; v < 8; v++) {
        int u  = v * 256 + t;
        int i  = u >> 6;
        int k4 = (u & 63) * 4;
        floatx4 x = *(const floatx4*)(input + (size_t)(i0 + i) * FIN + k4);
        bf16x4 b;
        #pragma unroll
        for (int e = 0; e < 4; e++) b[e] = (bf16_t)x[e];
        *(bf16x4*)(&in_lds[i][k4]) = b;
    }
    #pragma unroll
    for (int v = 0; v < 16; v++) {
        int u  = v * 256 + t;
        int k  = u >> 4;
        int f4 = (u & 15) * 4;
        floatx4 wv = *(const floatx4*)(W + k * FOUT + f4);
        #pragma unroll
        for (int e = 0; e < 4; e++) wt_lds[f4 + e][k] = (bf16_t)wv[e];
    }
    __syncthreads();

    const int wave = t >> 6;
    const int lane = t & 63;
    const int i16  = (wave & 1) * 16;
    const int f32  = (wave >> 1) * 32;
    const int lm   = lane & 15;
    const int lq   = lane >> 4;

    floatx4 acc0 = {0.f, 0.f, 0.f, 0.f};
    floatx4 acc1 = {0.f, 0.f, 0.f, 0.f};
    #pragma unroll
    for (int ks = 0; ks < 8; ks++) {
        int ko = ks * 32 + lq * 8;
        bf16x8 af = *(const bf16x8*)(&in_lds[i16 + lm][ko]);
        bf16x8 b0 = *(const bf16x8*)(&wt_lds[f32 + lm][ko]);
        bf16x8 b1 = *(const bf16x8*)(&wt_lds[f32 + 16 + lm][ko]);
        acc0 = __builtin_amdgcn_mfma_f32_16x16x32_bf16(af, b0, acc0, 0, 0, 0);
        acc1 = __builtin_amdgcn_mfma_f32_16x16x32_bf16(af, b1, acc1, 0, 0, 0);
    }

    #pragma unroll
    for (int c = 0; c < 2; c++) {
        floatx4 acc = c ? acc1 : acc0;
        int f  = f32 + c * 16 + lm;
        int ib = i0 + i16 + lq * 4;
        bf16x4 hp;
        #pragma unroll
        for (int r = 0; r < 4; r++) hp[r] = (bf16_t)acc[r];
        *(bf16x4*)(hT + (size_t)f * NN + ib) = hp;
    }
    #pragma unroll
    for (int c = 0; c < 2; c++) {
        floatx4 acc = c ? acc1 : acc0;
        #pragma unroll
        for (int r = 0; r < 4; r++)
            h_lds[i16 + lq * 4 + r][f32 + c * 16 + lm] = acc[r];
    }
    __syncthreads();

    if (t < 64) {
        int r   = t & 31;
        int sel = t >> 5;                       // 0 -> a1 (E1/F1), 1 -> a2 (ef2)
        const float* av = a + sel * FOUT;
        float s = 0.f;
        #pragma unroll 8
        for (int f = 0; f < FOUT; f++) s += h_lds[r][f] * av[f];
        int gi = i0 + r;
        float E = expf(s);
        float F = expf(GAT_ALPHA * s);
        if (sel == 0) {
            e1g[gi] = E; f1g[gi] = F;
        } else {
            unsigned eb = __builtin_bit_cast(unsigned short, (bf16_t)E);
            unsigned fb = __builtin_bit_cast(unsigned short, (bf16_t)F);
            ef2g[gi] = (fb << 16) | eb;
        }
    }
}

// ---------------------------------------------------------------------------
// Kernel B: barrier-free, LDS-free fused softmax+aggregation.
// Wave owns 16 rows x JSEG j's. Per 32-j step: adj (2x intx4), ef2 (2x uintx4),
// hT B-frags (4x bf16x8) -> w in A-frag layout in registers -> 4 MFMA.
// w = adj>0 ? max(E1*E2, F1*F2) : 0   [= exp(leaky_relu(s1+s2)) masked]
// Register double-buffer; compiler emits fine-grained vmcnt (no barriers).
// ---------------------------------------------------------------------------
#define LOADS(B, OFF)                                                          \
    {                                                                          \
        adjb[B][0] = *(const intx4*)(adjrow + (OFF));                          \
        adjb[B][1] = *(const intx4*)(adjrow + (OFF) + 4);                      \
        efb[B][0]  = *(const uintx4*)(efp + (OFF));                            \
        efb[B][1]  = *(const uintx4*)(efp + (OFF) + 4);                        \
        _Pragma("unroll")                                                      \
        for (int c = 0; c < 4; c++)                                            \
            htb[B][c] = *(const bf16x8*)(htp + (size_t)c * 16 * NN + (OFF));   \
    }

#define CONSUME(B)                                                             \
    {                                                                          \
        bf16x8 wf;                                                             \
        _Pragma("unroll")                                                      \
        for (int e = 0; e < 8; e++) {                                          \
            int av      = (e < 4) ? adjb[B][0][e] : adjb[B][1][e - 4];         \
            unsigned v  = (e < 4) ? efb[B][0][e] : efb[B][1][e - 4];           \
            float e2 = __builtin_bit_cast(float, v << 16);                     \
            float f2 = __builtin_bit_cast(float, v & 0xffff0000u);             \
            float p  = fmaxf(E1 * e2, F1 * f2);                                \
            float wv = (av > 0) ? p : 0.f;                                     \
            bf16_t wb = (bf16_t)wv;                                            \
            wf[e] = wb;                                                        \
            rowsum += (float)wb;                                               \
        }                                                                      \
        _Pragma("unroll")                                                      \
        for (int c = 0; c < 4; c++)                                            \
            acc[c] = __builtin_amdgcn_mfma_f32_16x16x32_bf16(                  \
                wf, htb[B][c], acc[c], 0, 0, 0);                               \
    }

__global__ __launch_bounds__(256, 4) void gat_att_kernel(
    const int* __restrict__ adj,        // [8192][8192] int32
    const bf16_t* __restrict__ hT,      // [64][8192] bf16
    const float* __restrict__ e1g, const float* __restrict__ f1g,
    const unsigned* __restrict__ ef2g,  // [8192] packed
    float* __restrict__ pacc,           // [JSPLIT][8192][64]
    float* __restrict__ prs)            // [JSPLIT][8192]
{
    const int t    = threadIdx.x;
    const int wave = t >> 6;
    const int lane = t & 63;
    const int m    = lane & 15;         // row within 16 (A-frag) / f (B/C col)
    const int q    = lane >> 4;         // quad: k = q*8+e
    const int i0   = blockIdx.x * 64 + wave * 16;
    const int js   = blockIdx.y;
    const int row  = i0 + m;

    const float E1 = e1g[row];
    const float F1 = f1g[row];

    const int*      adjrow = adj + (size_t)row * NN + js * JSEG + q * 8;
    const unsigned* efp    = ef2g + js * JSEG + q * 8;
    const bf16_t*   htp    = hT + (size_t)m * NN + js * JSEG + q * 8;

    floatx4 acc[4];
    #pragma unroll
    for (int c = 0; c < 4; c++) acc[c] = (floatx4){0.f, 0.f, 0.f, 0.f};
    float rowsum = 0.f;

    intx4  adjb[2][2];
    uintx4 efb[2][2];
    bf16x8 htb[2][4];

    LOADS(0, 0);
    for (int s = 0; s < NSTEP; s += 2) {
        LOADS(1, (s + 1) * 32);
        CONSUME(0);
        if (s + 2 < NSTEP) LOADS(0, (s + 2) * 32);
        CONSUME(1);
    }

    // rowsum: reduce across the 4 quads holding row m
    rowsum += __shfl_xor(rowsum, 16, 64);
    rowsum += __shfl_xor(rowsum, 32, 64);
    if (lane < 16) prs[(size_t)js * NN + i0 + lane] = rowsum;

    // partial acc: C layout col=m (f), row=q*4+r
    float* pa = pacc + (size_t)js * NN * FOUT;
    #pragma unroll
    for (int c = 0; c < 4; c++) {
        #pragma unroll
        for (int r = 0; r < 4; r++)
            pa[(size_t)(i0 + q * 4 + r) * FOUT + c * 16 + m] = acc[c][r];
    }
}

// ---------------------------------------------------------------------------
// Kernel C: combine JSPLIT partials, normalize, ELU, store fp32.
// ---------------------------------------------------------------------------
__global__ __launch_bounds__(256) void gat_combine_kernel(
    const float* __restrict__ pacc,     // [JSPLIT][8192][64]
    const float* __restrict__ prs,      // [JSPLIT][8192]
    float* __restrict__ out)            // [8192][64]
{
    int idx = blockIdx.x * 256 + threadIdx.x;   // one float4 group
    int i   = idx >> 4;
    floatx4 s = {0.f, 0.f, 0.f, 0.f};
    float rs  = 0.f;
    #pragma unroll
    for (int js = 0; js < JSPLIT; js++) {
        s  += *(const floatx4*)(pacc + (size_t)js * NN * FOUT + (size_t)idx * 4);
        rs += prs[(size_t)js * NN + i];
    }
    float rinv = (rs > 0.f) ? 1.0f / rs : 0.f;
    floatx4 r;
    #pragma unroll
    for (int e = 0; e < 4; e++) {
        float x = s[e] * rinv;
        r[e] = (x > 0.f) ? x : (expf(x) - 1.0f);
    }
    *(floatx4*)(out + (size_t)idx * 4) = r;
}

// ---------------------------------------------------------------------------
extern "C" void kernel_launch(void* const* d_in, const int* in_sizes, int n_in,
                              void* d_out, int out_size, void* d_ws, size_t ws_size,
                              hipStream_t stream) {
    const float* input = (const float*)d_in[0];     // [8192][256] fp32
    const int*   adj   = (const int*)d_in[1];       // [8192][8192] int32
    const float* W     = (const float*)d_in[2];     // [256][64] fp32
    const float* a     = (const float*)d_in[3];     // [128] fp32
    float*       out   = (float*)d_out;             // [8192][64] fp32

    char* ws = (char*)d_ws;
    bf16_t*   hT   = (bf16_t*)ws;                   // 1 MiB
    float*    e1g  = (float*)(ws + (1 << 20));
    float*    f1g  = e1g + NN;
    unsigned* ef2g = (unsigned*)(f1g + NN);
    float*    pacc = (float*)(ef2g + NN);           // JSPLIT*8192*64*4 = 16 MiB
    float*    prs  = pacc + (size_t)JSPLIT * NN * FOUT;

    gat_h_kernel<<<NN / 32, 256, 0, stream>>>(input, W, a, hT, e1g, f1g, ef2g);

    dim3 gridB(NN / 64, JSPLIT);
    gat_att_kernel<<<gridB, 256, 0, stream>>>(adj, hT, e1g, f1g, ef2g,
                                              pacc, prs);

    gat_combine_kernel<<<NN * FOUT / 4 / 256, 256, 0, stream>>>(pacc, prs, out);
}